// Round 1
// baseline (161.753 us; speedup 1.0000x reference)
//
#include <hip/hip_runtime.h>

#define D 4096

// ---------------- pass 1: reductions ----------------

// Column sums (sum over axis 0). grid (D/1024, D/ROWS), block 256.
// Each thread owns 4 consecutive columns (float4), accumulates ROWS rows,
// then one atomicAdd per column.
__global__ void colsum_kernel(const float* __restrict__ A, float* __restrict__ out) {
    const int ROWS = 64;
    int c4 = blockIdx.x * blockDim.x + threadIdx.x;   // float4-column index
    int r0 = blockIdx.y * ROWS;
    const float4* A4 = (const float4*)A;
    float4 s = make_float4(0.f, 0.f, 0.f, 0.f);
    for (int r = 0; r < ROWS; ++r) {
        float4 v = A4[(size_t)(r0 + r) * (D / 4) + c4];
        s.x += v.x; s.y += v.y; s.z += v.z; s.w += v.w;
    }
    atomicAdd(&out[c4 * 4 + 0], s.x);
    atomicAdd(&out[c4 * 4 + 1], s.y);
    atomicAdd(&out[c4 * 4 + 2], s.z);
    atomicAdd(&out[c4 * 4 + 3], s.w);
}

// Row sums (sum over axis 1). grid D, block 256. One block per row.
__global__ void rowsum_kernel(const float* __restrict__ A, float* __restrict__ out) {
    int row = blockIdx.x;
    const float4* A4 = (const float4*)(A + (size_t)row * D);
    float s = 0.f;
    for (int i = threadIdx.x; i < D / 4; i += blockDim.x) {
        float4 v = A4[i];
        s += (v.x + v.y) + (v.z + v.w);
    }
    for (int o = 32; o > 0; o >>= 1) s += __shfl_down(s, o);   // wave64 reduce
    __shared__ float red[4];
    int lane = threadIdx.x & 63, wid = threadIdx.x >> 6;
    if (lane == 0) red[wid] = s;
    __syncthreads();
    if (threadIdx.x == 0) out[row] = (red[0] + red[1]) + (red[2] + red[3]);
}

// ---------------- pass 2: message chain (single block) ----------------

__device__ float block_sum_1024(float v, float* red) {
    for (int o = 32; o > 0; o >>= 1) v += __shfl_down(v, o);
    int lane = threadIdx.x & 63, wid = threadIdx.x >> 6;
    if (lane == 0) red[wid] = v;
    __syncthreads();
    if (threadIdx.x == 0) {
        float t = 0.f;
        for (int w = 0; w < 16; ++w) t += red[w];
        red[0] = t;
    }
    __syncthreads();
    return red[0];
}

// ws layout (floats): [0:colsum0][D:colsum1][2D:rowsum1][3D:rowsum2]
//                     [4D:m0][5D:m1][6D:m2][7D:m3]
__global__ void __launch_bounds__(1024) messages_kernel(
        const float* __restrict__ ws,
        const int* __restrict__ op0, const int* __restrict__ op1,
        const int* __restrict__ op2, const int* __restrict__ op3,
        float* __restrict__ ws_w) {
    const float* colsum0 = ws;
    const float* colsum1 = ws + D;
    const float* rowsum1 = ws + 2 * D;
    const float* rowsum2 = ws + 3 * D;
    float* g_m0 = ws_w + 4 * D;
    float* g_m1 = ws_w + 5 * D;
    float* g_m2 = ws_w + 6 * D;
    float* g_m3 = ws_w + 7 * D;   // pre-zeroed by memset; global atomics

    __shared__ float m0[D], m1[D], m2[D];
    __shared__ float red[16];
    int tid = threadIdx.x;

    for (int i = tid; i < D; i += 1024) { m0[i] = 0.f; m1[i] = 0.f; m2[i] = 0.f; }
    __syncthreads();

    // m0 = remap(colsum0, op0)
    for (int i = tid; i < D; i += 1024)
        atomicAdd(&m0[op0[D + i]], colsum0[op0[i]]);
    __syncthreads();

    // S0 = sum(m0)
    float p = 0.f;
    for (int i = tid; i < D; i += 1024) p += m0[i];
    float S0 = block_sum_1024(p, red);

    // m1 = remap(colsum1 + S0, op1)
    for (int i = tid; i < D; i += 1024)
        atomicAdd(&m1[op1[D + i]], colsum1[op1[i]] + S0);
    __syncthreads();

    // m2 = remap(rowsum2 + 4095*m1, op2)
    for (int i = tid; i < D; i += 1024) {
        int src = op2[i];
        atomicAdd(&m2[op2[D + i]], rowsum2[src] + 4095.0f * m1[src]);
    }
    __syncthreads();

    // S2 = sum(m2)
    p = 0.f;
    for (int i = tid; i < D; i += 1024) p += m2[i];
    float S2 = block_sum_1024(p, red);

    // m3 = remap(rowsum1 + 4095*m0 + S2, op3) -> global atomics (never re-read here)
    for (int i = tid; i < D; i += 1024) {
        int src = op3[i];
        atomicAdd(&g_m3[op3[D + i]], rowsum1[src] + 4095.0f * m0[src] + S2);
    }

    // export m0..m2
    for (int i = tid; i < D; i += 1024) {
        g_m0[i] = m0[i]; g_m1[i] = m1[i]; g_m2[i] = m2[i];
    }
}

// ---------------- pass 3: apply broadcasts ----------------

// grid 3*D blocks, block 256. Block b handles row (b & 4095) of matrix (b >> 12).
__global__ void apply_kernel(const float* __restrict__ t0, const float* __restrict__ t1,
                             const float* __restrict__ t2, const float* __restrict__ msgs,
                             float* __restrict__ out) {
    int b = blockIdx.x;
    int mat = b >> 12;
    int row = b & (D - 1);
    const float* m0 = msgs + 0 * D;
    const float* m1 = msgs + 1 * D;
    const float* m2 = msgs + 2 * D;
    const float* m3 = msgs + 3 * D;
    size_t base = (size_t)row * D;
    float4* dst = (float4*)(out + (size_t)mat * D * D + base);

    if (mat == 0) {
        const float4* src = (const float4*)(t0 + base);
        const float4* c4 = (const float4*)m3;
        for (int i = threadIdx.x; i < D / 4; i += blockDim.x) {
            float4 v = src[i], c = c4[i];
            dst[i] = make_float4(v.x + c.x, v.y + c.y, v.z + c.z, v.w + c.w);
        }
    } else if (mat == 1) {
        const float4* src = (const float4*)(t1 + base);
        const float4* c4 = (const float4*)m2;
        float r = m0[row];
        for (int i = threadIdx.x; i < D / 4; i += blockDim.x) {
            float4 v = src[i], c = c4[i];
            dst[i] = make_float4(v.x + r + c.x, v.y + r + c.y, v.z + r + c.z, v.w + r + c.w);
        }
    } else {
        const float4* src = (const float4*)(t2 + base);
        float r = m1[row];
        for (int i = threadIdx.x; i < D / 4; i += blockDim.x) {
            float4 v = src[i];
            dst[i] = make_float4(v.x + r, v.y + r, v.z + r, v.w + r);
        }
    }
}

extern "C" void kernel_launch(void* const* d_in, const int* in_sizes, int n_in,
                              void* d_out, int out_size, void* d_ws, size_t ws_size,
                              hipStream_t stream) {
    const float* t0 = (const float*)d_in[0];
    const float* t1 = (const float*)d_in[1];
    const float* t2 = (const float*)d_in[2];
    const int* op0 = (const int*)d_in[3];
    const int* op1 = (const int*)d_in[4];
    const int* op2 = (const int*)d_in[5];
    const int* op3 = (const int*)d_in[6];
    float* out = (float*)d_out;
    float* ws = (float*)d_ws;

    // zero the atomic-accumulated regions: colsum0, colsum1 (ws[0:2D]) and m3 (ws[7D:8D])
    hipMemsetAsync(ws, 0, 2 * D * sizeof(float), stream);
    hipMemsetAsync(ws + 7 * D, 0, D * sizeof(float), stream);

    dim3 csGrid(D / 1024, D / 64);
    colsum_kernel<<<csGrid, 256, 0, stream>>>(t0, ws);           // colsum0
    colsum_kernel<<<csGrid, 256, 0, stream>>>(t1, ws + D);       // colsum1
    rowsum_kernel<<<D, 256, 0, stream>>>(t1, ws + 2 * D);        // rowsum1
    rowsum_kernel<<<D, 256, 0, stream>>>(t2, ws + 3 * D);        // rowsum2

    messages_kernel<<<1, 1024, 0, stream>>>(ws, op0, op1, op2, op3, ws);

    apply_kernel<<<3 * D, 256, 0, stream>>>(t0, t1, t2, ws + 4 * D, out);
}

// Round 3
// 143.800 us; speedup vs baseline: 1.1248x; 1.1248x over previous
//
#include <hip/hip_runtime.h>

#define D 4096

typedef float fx4 __attribute__((ext_vector_type(4)));

// ws layout (floats):
//   [0:D)    colsum0   (global atomics, memset to 0 first)
//   [D:2D)   colsum1   (global atomics, memset to 0 first)
//   [2D:3D)  rowsum1   (direct store)
//   [3D:4D)  rowsum2   (direct store)
//   [4D:5D)  m0  [5D:6D) m1  [6D:7D) m2  [7D:8D) m3   (messages exports)

// ---------------- pass 1: all four reductions in one launch ----------------
// grid 2560 blocks x 256 threads:
//   [0,256)     colsum t0 -> ws[0:D)      (thread owns a float4 column, 64-row stripe)
//   [256,512)   colsum t1 -> ws[D:2D)
//   [512,1536)  rowsum t1 -> ws[2D:3D)    (wave per row, 4 rows/block)
//   [1536,2560) rowsum t2 -> ws[3D:4D)
__global__ void __launch_bounds__(256) reduce_all_kernel(
        const float* __restrict__ t0, const float* __restrict__ t1,
        const float* __restrict__ t2, float* __restrict__ ws) {
    int b = blockIdx.x;
    if (b < 512) {
        const float* A = (b < 256) ? t0 : t1;
        float* out = ws + ((b < 256) ? 0 : D);
        int lb = b & 255;
        int c4 = (lb & 3) * 256 + threadIdx.x;     // float4-column index, 0..1023
        int r0 = (lb >> 2) * 64;                   // stripe of 64 rows
        const fx4* A4 = (const fx4*)A;
        fx4 s = (fx4){0.f, 0.f, 0.f, 0.f};
        #pragma unroll 8
        for (int r = 0; r < 64; ++r) {
            s += A4[(size_t)(r0 + r) * (D / 4) + c4];
        }
        atomicAdd(&out[c4 * 4 + 0], s.x);
        atomicAdd(&out[c4 * 4 + 1], s.y);
        atomicAdd(&out[c4 * 4 + 2], s.z);
        atomicAdd(&out[c4 * 4 + 3], s.w);
    } else {
        int lb = (b - 512) & 1023;                 // 0..1023
        const float* A = (b < 1536) ? t1 : t2;
        float* out = ws + ((b < 1536) ? 2 * D : 3 * D);
        int wid = threadIdx.x >> 6, lane = threadIdx.x & 63;
        int row = lb * 4 + wid;
        const fx4* A4 = (const fx4*)(A + (size_t)row * D);
        float s = 0.f;
        #pragma unroll 4
        for (int i = lane; i < D / 4; i += 64) {
            fx4 v = A4[i];
            s += (v.x + v.y) + (v.z + v.w);
        }
        #pragma unroll
        for (int o = 32; o > 0; o >>= 1) s += __shfl_down(s, o);
        if (lane == 0) out[row] = s;
    }
}

// ---------------- pass 2: message chain (single block, prefetched) ----------------

__device__ __forceinline__ float block_sum_1024(float v, float* red) {
    #pragma unroll
    for (int o = 32; o > 0; o >>= 1) v += __shfl_down(v, o);
    int lane = threadIdx.x & 63, wid = threadIdx.x >> 6;
    if (lane == 0) red[wid] = v;
    __syncthreads();
    if (threadIdx.x == 0) {
        float t = 0.f;
        #pragma unroll
        for (int w = 0; w < 16; ++w) t += red[w];
        red[0] = t;
    }
    __syncthreads();
    float r = red[0];
    __syncthreads();
    return r;
}

__global__ void __launch_bounds__(1024) messages_kernel(
        const float* __restrict__ ws,
        const int* __restrict__ op0, const int* __restrict__ op1,
        const int* __restrict__ op2, const int* __restrict__ op3,
        float* __restrict__ ws_w) {
    const float* colsum0 = ws;
    const float* colsum1 = ws + D;
    const float* rowsum1 = ws + 2 * D;
    const float* rowsum2 = ws + 3 * D;

    __shared__ float m0[D], m1[D], m2[D], m3[D];
    __shared__ float red[16];
    int tid = threadIdx.x;

    // prefetch all op indices (issue loads up front; independent)
    int s0[4], d0[4], s1[4], d1[4], s2[4], d2[4], s3[4], d3[4];
    #pragma unroll
    for (int k = 0; k < 4; ++k) {
        int i = tid + k * 1024;
        s0[k] = op0[i]; d0[k] = op0[D + i];
        s1[k] = op1[i]; d1[k] = op1[D + i];
        s2[k] = op2[i]; d2[k] = op2[D + i];
        s3[k] = op3[i]; d3[k] = op3[D + i];
    }
    // prefetch all global gathers — none depend on earlier messages
    float g0[4], g1[4], g2[4], g3[4];
    #pragma unroll
    for (int k = 0; k < 4; ++k) {
        g0[k] = colsum0[s0[k]];
        g1[k] = colsum1[s1[k]];
        g2[k] = rowsum2[s2[k]];
        g3[k] = rowsum1[s3[k]];
    }

    #pragma unroll
    for (int k = 0; k < 4; ++k) {
        int i = tid + k * 1024;
        m0[i] = 0.f; m1[i] = 0.f; m2[i] = 0.f; m3[i] = 0.f;
    }
    __syncthreads();

    // m0 = remap(colsum0, op0)
    #pragma unroll
    for (int k = 0; k < 4; ++k) atomicAdd(&m0[d0[k]], g0[k]);
    __syncthreads();

    // S0 = sum(m0)
    float p = 0.f;
    #pragma unroll
    for (int k = 0; k < 4; ++k) p += m0[tid + k * 1024];
    float S0 = block_sum_1024(p, red);

    // m1 = remap(colsum1 + S0, op1)
    #pragma unroll
    for (int k = 0; k < 4; ++k) atomicAdd(&m1[d1[k]], g1[k] + S0);
    __syncthreads();

    // m2 = remap(rowsum2 + 4095*m1, op2)
    #pragma unroll
    for (int k = 0; k < 4; ++k)
        atomicAdd(&m2[d2[k]], g2[k] + 4095.0f * m1[s2[k]]);
    __syncthreads();

    // S2 = sum(m2)
    p = 0.f;
    #pragma unroll
    for (int k = 0; k < 4; ++k) p += m2[tid + k * 1024];
    float S2 = block_sum_1024(p, red);

    // m3 = remap(rowsum1 + 4095*m0 + S2, op3)
    #pragma unroll
    for (int k = 0; k < 4; ++k)
        atomicAdd(&m3[d3[k]], g3[k] + 4095.0f * m0[s3[k]] + S2);
    __syncthreads();

    // export
    #pragma unroll
    for (int k = 0; k < 4; ++k) {
        int i = tid + k * 1024;
        ws_w[4 * D + i] = m0[i];
        ws_w[5 * D + i] = m1[i];
        ws_w[6 * D + i] = m2[i];
        ws_w[7 * D + i] = m3[i];
    }
}

// ---------------- pass 3: apply broadcasts ----------------
// grid 3*D blocks x 256; block b: row (b & 4095) of matrix (b >> 12).
__global__ void __launch_bounds__(256) apply_kernel(
        const float* __restrict__ t0, const float* __restrict__ t1,
        const float* __restrict__ t2, const float* __restrict__ msgs,
        float* __restrict__ out) {
    int b = blockIdx.x;
    int mat = b >> 12;
    int row = b & (D - 1);
    const float* m0 = msgs + 0 * D;
    const float* m1 = msgs + 1 * D;
    const float* m2 = msgs + 2 * D;
    const float* m3 = msgs + 3 * D;
    size_t base = (size_t)row * D;
    fx4* dst = (fx4*)(out + (size_t)mat * D * D + base);

    if (mat == 0) {
        const fx4* src = (const fx4*)(t0 + base);
        const fx4* c4 = (const fx4*)m3;
        for (int i = threadIdx.x; i < D / 4; i += 256) {
            fx4 r = src[i] + c4[i];
            __builtin_nontemporal_store(r, &dst[i]);
        }
    } else if (mat == 1) {
        const fx4* src = (const fx4*)(t1 + base);
        const fx4* c4 = (const fx4*)m2;
        float rr = m0[row];
        for (int i = threadIdx.x; i < D / 4; i += 256) {
            fx4 r = src[i] + c4[i] + rr;
            __builtin_nontemporal_store(r, &dst[i]);
        }
    } else {
        const fx4* src = (const fx4*)(t2 + base);
        float rr = m1[row];
        for (int i = threadIdx.x; i < D / 4; i += 256) {
            fx4 r = src[i] + rr;
            __builtin_nontemporal_store(r, &dst[i]);
        }
    }
}

extern "C" void kernel_launch(void* const* d_in, const int* in_sizes, int n_in,
                              void* d_out, int out_size, void* d_ws, size_t ws_size,
                              hipStream_t stream) {
    const float* t0 = (const float*)d_in[0];
    const float* t1 = (const float*)d_in[1];
    const float* t2 = (const float*)d_in[2];
    const int* op0 = (const int*)d_in[3];
    const int* op1 = (const int*)d_in[4];
    const int* op2 = (const int*)d_in[5];
    const int* op3 = (const int*)d_in[6];
    float* out = (float*)d_out;
    float* ws = (float*)d_ws;

    // zero only the global-atomic targets: colsum0, colsum1
    hipMemsetAsync(ws, 0, 2 * D * sizeof(float), stream);

    reduce_all_kernel<<<2560, 256, 0, stream>>>(t0, t1, t2, ws);
    messages_kernel<<<1, 1024, 0, stream>>>(ws, op0, op1, op2, op3, ws);
    apply_kernel<<<3 * D, 256, 0, stream>>>(t0, t1, t2, ws + 4 * D, out);
}